// Round 1
// 608.321 us; speedup vs baseline: 1.0461x; 1.0461x over previous
//
#include <hip/hip_runtime.h>
#include <hip/hip_bf16.h>
#include <cstdint>
#include <cstddef>

// Problem constants
#define B_TOK 8192
#define HID   4096
#define NH    32
#define NKV   8
#define DH    128
#define RB    128
#define KDIM  4096
#define NOUT  5120   // q (32*128) + k (8*128) columns; v columns are never used
#define QKVW  6144

typedef __bf16 bf16x8 __attribute__((ext_vector_type(8)));
typedef __bf16 bf16x4 __attribute__((ext_vector_type(4)));
typedef float  f32x4  __attribute__((ext_vector_type(4)));

// ---- async global->LDS, 16B per lane. LDS dest = wave-uniform base + lane*16 ----
__device__ __forceinline__ void async_ld16(const void* g, void* l) {
  __builtin_amdgcn_global_load_lds(
      (__attribute__((address_space(1))) void*)(g),
      (__attribute__((address_space(3))) void*)(l), 16, 0, 0);
}

// (tanh(x)+1)/2 == sigmoid(2x) = 1/(1+exp2(-2*log2e*x))
__device__ __forceinline__ float code_of(float x) {
  const float e = exp2f(x * -2.885390081777927f);
  return __builtin_amdgcn_rcpf(1.0f + e);
}

// ---------------- fused prep kernel (unchanged) ----------------

#define NB_HID  16384
#define NB_WT   5120   // 80 n-tiles x 64 k-tiles
#define NB_HASH 64

__global__ void prep_kernel(const float* __restrict__ hidden, __bf16* __restrict__ Abf,
                            const float* __restrict__ W, __bf16* __restrict__ Wt,
                            const float* __restrict__ hw, __bf16* __restrict__ hwT) {
  __shared__ float t[64][65];
  const int bx  = blockIdx.x;
  const int tid = threadIdx.x;

  if (bx < NB_HID) {
    const int i = bx * 256 + tid;
    const float4 v0 = ((const float4*)hidden)[2 * i];
    const float4 v1 = ((const float4*)hidden)[2 * i + 1];
    bf16x8 o;
    o[0] = (__bf16)v0.x; o[1] = (__bf16)v0.y; o[2] = (__bf16)v0.z; o[3] = (__bf16)v0.w;
    o[4] = (__bf16)v1.x; o[5] = (__bf16)v1.y; o[6] = (__bf16)v1.z; o[7] = (__bf16)v1.w;
    ((bf16x8*)Abf)[i] = o;
  } else if (bx < NB_HID + NB_WT) {
    const int bt = bx - NB_HID;
    const int n0 = (bt % 80) * 64;   // over NOUT
    const int k0 = (bt / 80) * 64;   // over KDIM
    const int c4 = tid & 15;
    const int rr = tid >> 4;         // 0..15
#pragma unroll
    for (int j = 0; j < 4; ++j) {
      const int r = rr + j * 16;
      const float4 v = *(const float4*)&W[(size_t)(k0 + r) * QKVW + n0 + c4 * 4];
      t[r][c4 * 4 + 0] = v.x; t[r][c4 * 4 + 1] = v.y;
      t[r][c4 * 4 + 2] = v.z; t[r][c4 * 4 + 3] = v.w;
    }
    __syncthreads();
    const int c8 = tid & 7;
    const int nn = tid >> 3;         // 0..31
#pragma unroll
    for (int jj = 0; jj < 2; ++jj) {
      const int n = nn + jj * 32;
      bf16x8 o;
#pragma unroll
      for (int i = 0; i < 8; ++i) o[i] = (__bf16)t[c8 * 8 + i][n];
      *(bf16x8*)&Wt[(size_t)(n0 + n) * KDIM + k0 + c8 * 8] = o;
    }
  } else {
    const int idx = (bx - NB_HID - NB_WT) * 256 + tid;  // 16384 elems
    const int r = idx >> 7;    // rbit
    const int d = idx & 127;   // dim
    hwT[r * RB + d] = (__bf16)hw[(size_t)d * RB + r];   // write coalesced
  }
}

// ---------------- main GEMM: C[8192][5120] = A[8192][4096] @ Bt[5120][4096]^T + bias ----
// Ring-3 counted-vmcnt pipeline (T3+T4 mechanism, structurally race-free):
//  * BM=128, BN=256, BK=32. 256 threads = 4 waves (2M x 2N), per-wave 64x128 output.
//  * LDS = 3 slots x (A 8KB + B 16KB) = 72KB -> 2 blocks/CU; grid 64x20 = 1280 = 5/CU
//    exactly (256^2 tiles would give 640 = 2.5/CU tail).
//  * Per K-tile: vmcnt(6) [counted: next tile's 6 loads stay IN FLIGHT across the
//    barrier] -> s_barrier -> sched_barrier(0) -> stage tile t+2 into slot of t-1
//    (dead: every wave passed the barrier after consuming t-1) -> 12 ds_read_b128
//    -> setprio(1) 32 MFMA setprio(0).  No vmcnt(0) drain in steady state.
//  * LDS chunk-XOR swizzle (rule-21 both-sides): physical 16B-chunk p of row r holds
//    logical chunk p ^ ((r>>1)&3). Stage pre-swizzles the GLOBAL source k-offset
//    (lane-constant), reads XOR the chunk index (lane-constant) -> ds_read_b128
//    lands 2 lanes/bank-group (free) instead of 8-way.
//  * XCD swizzle: xcd = lin&7 owns an 8-m-tile strip; the 8 co-resident blocks of an
//    XCD walk n together -> shared B panel is L2-hot.

#define BK    32
#define KT    (KDIM / BK)       // 128
#define SLOT  24576             // A: 8192 B, B: 16384 B

__global__ __launch_bounds__(256, 2) void gemm_qk(const __bf16* __restrict__ A,
                                                  const __bf16* __restrict__ Bt,
                                                  const float* __restrict__ bias,
                                                  __bf16* __restrict__ C) {
  __shared__ __align__(1024) char smem[3 * SLOT];

  const int tid  = threadIdx.x;
  const int lane = tid & 63;
  const int wave = tid >> 6;
  const int wm   = wave >> 1;      // 0..1  (m half)
  const int wn   = wave & 1;       // 0..1  (n half)

  // XCD swizzle: bijective on 1280 = 8 xcd x (20 n x 8 m)
  const int lin = blockIdx.x;
  const int xcd = lin & 7;
  const int seq = lin >> 3;                    // 0..159
  const int m0  = (xcd * 8 + (seq & 7)) * 128;
  const int n0  = (seq >> 3) * 256;

  // staging: lane writes physical chunk (tid&3) of row (r*64 + tid>>2);
  // pre-swizzled source fetches logical chunk (tid&3) ^ ((tid>>3)&3)
  const int srow = tid >> 2;                                  // 0..63
  const int sxk  = ((tid & 3) ^ ((tid >> 3) & 3)) * 8;        // elems
  const __bf16* ga = A  + (size_t)(m0 + srow) * KDIM + sxk;
  const __bf16* gb = Bt + (size_t)(n0 + srow) * KDIM + sxk;
  const int ldsA = wave * 1024;   // wave-uniform chunk within each 4KB round

#define STAGE(koff, sl) do {                                        \
    const __bf16* ga_ = ga + (koff);                                \
    const __bf16* gb_ = gb + (koff);                                \
    async_ld16(ga_,              (sl) + ldsA);                      \
    async_ld16(ga_ +  64 * KDIM, (sl) + 4096  + ldsA);              \
    async_ld16(gb_,              (sl) + 8192  + ldsA);              \
    async_ld16(gb_ +  64 * KDIM, (sl) + 12288 + ldsA);              \
    async_ld16(gb_ + 128 * KDIM, (sl) + 16384 + ldsA);              \
    async_ld16(gb_ + 192 * KDIM, (sl) + 20480 + ldsA);              \
  } while (0)

  // fragment reads: logical (row = base16 + fr, chunk hi) at physical chunk
  // hi ^ ((fr>>1)&3)  -- lane-constant XOR, zero extra VALU in the loop
  const int fr = lane & 15;
  const int xc = (lane >> 4) ^ ((fr >> 1) & 3);
  const int aoff = (wm * 64 + fr) * 64 + xc * 16;    // bytes into slot A
  const int boff = (wn * 128 + fr) * 64 + xc * 16;   // bytes into slot B region

  f32x4 acc[4][8] = {};

#define COMPUTE(sl) do {                                                          \
    bf16x8 af[4]; bf16x8 bfv[8];                                                  \
    _Pragma("unroll")                                                             \
    for (int mi = 0; mi < 4; ++mi)                                                \
      af[mi] = *(const bf16x8*)((sl) + aoff + mi * 1024);                         \
    _Pragma("unroll")                                                             \
    for (int ni = 0; ni < 8; ++ni)                                                \
      bfv[ni] = *(const bf16x8*)((sl) + 8192 + boff + ni * 1024);                 \
    __builtin_amdgcn_s_setprio(1);                                                \
    _Pragma("unroll")                                                             \
    for (int mi = 0; mi < 4; ++mi)                                                \
      _Pragma("unroll")                                                           \
      for (int ni = 0; ni < 8; ++ni)                                              \
        acc[mi][ni] = __builtin_amdgcn_mfma_f32_16x16x32_bf16(af[mi], bfv[ni],    \
                                                              acc[mi][ni], 0, 0, 0); \
    __builtin_amdgcn_s_setprio(0);                                                \
  } while (0)

  char* s0 = smem;              // compute slot (tile t)
  char* s1 = smem + SLOT;       // tile t+1 (in flight / landed)
  char* s2 = smem + 2 * SLOT;   // stage target (tile t+2; held t-1 before)

  STAGE(0, s0);
  STAGE(BK, s1);

  for (int t = 0; t < KT - 1; ++t) {
    // counted wait: all but the newest 6 loads (tile t+1's) retired => tile t landed
    asm volatile("s_waitcnt vmcnt(6)" ::: "memory");
    __builtin_amdgcn_s_barrier();
    __builtin_amdgcn_sched_barrier(0);
    if (t < KT - 2) STAGE((t + 2) * BK, s2);
    COMPUTE(s0);
    char* tmp = s0; s0 = s1; s1 = s2; s2 = tmp;
  }
  asm volatile("s_waitcnt vmcnt(0)" ::: "memory");
  __builtin_amdgcn_s_barrier();
  __builtin_amdgcn_sched_barrier(0);
  COMPUTE(s0);

#undef STAGE
#undef COMPUTE

  // epilogue: D layout col=lane&15, row=(lane>>4)*4+reg
  const int cl = lane & 15;
  const int rq = (lane >> 4) * 4;
#pragma unroll
  for (int ni = 0; ni < 8; ++ni) {
    const int gn = n0 + wn * 128 + ni * 16 + cl;
    const float bb = bias[gn];
#pragma unroll
    for (int mi = 0; mi < 4; ++mi) {
      const int gm = m0 + wm * 64 + mi * 16 + rq;
#pragma unroll
      for (int r = 0; r < 4; ++r)
        C[(size_t)(gm + r) * NOUT + gn] = (__bf16)(acc[mi][ni][r] + bb);
    }
  }
}

// ---------------- phase 2: per-token dots/norms/hash codes (unchanged) ----------------

__global__ void phase2_kernel(const __bf16* __restrict__ QK,
                              const __bf16* __restrict__ hwT,
                              float* __restrict__ out) {
  __shared__ __bf16 As[48][136];    // +8 bf16 pad -> conflict-free ds_read_b128
  __shared__ float code[40][132];   // (tanh+1)/2 codes
  __shared__ float rednorm[40];
  __shared__ float reddot[32];

  const int tid  = threadIdx.x;
  const int lane = tid & 63;
  const int wave = tid >> 6;
  const int b = blockIdx.x;

  const __bf16* src = QK + (size_t)b * NOUT;
  for (int i = tid; i < 640; i += 256) {
    const int row = i >> 4;
    const int col = (i & 15) * 8;
    *(uint4*)(&As[row][col]) = *(const uint4*)(src + i * 8);
  }

  const int fr = lane & 15;
  const int fk = (lane >> 4) * 8;
  bf16x8 bf[2][4];
#pragma unroll
  for (int nn = 0; nn < 2; ++nn) {
    const int ni = wave + nn * 4;
#pragma unroll
    for (int ks = 0; ks < 4; ++ks)
      bf[nn][ks] = *(const bf16x8*)(hwT + (size_t)(ni * 16 + fr) * RB + ks * 32 + fk);
  }
  __syncthreads();

#pragma unroll
  for (int mi = 0; mi < 3; ++mi) {
    bf16x8 af[4];
#pragma unroll
    for (int ks = 0; ks < 4; ++ks)
      af[ks] = *(const bf16x8*)(&As[mi * 16 + fr][ks * 32 + fk]);
#pragma unroll
    for (int nn = 0; nn < 2; ++nn) {
      const int ni = wave + nn * 4;
      f32x4 acc = {0.f, 0.f, 0.f, 0.f};
#pragma unroll
      for (int ks = 0; ks < 4; ++ks)
        acc = __builtin_amdgcn_mfma_f32_16x16x32_bf16(af[ks], bf[nn][ks], acc, 0, 0, 0);
      const int row0 = mi * 16 + (lane >> 4) * 4;
      const int col  = ni * 16 + (lane & 15);
#pragma unroll
      for (int r = 0; r < 4; ++r) {
        const int row = row0 + r;
        if (row < 40) code[row][col] = code_of(acc[r]);
      }
    }
  }

  {
    const int q = lane >> 4;
    const int c = lane & 15;
    const int ti = (wave == 1 || wave == 3) ? 1 : 0;
    const int tj = (wave >= 2) ? 2 : ti;
    bf16x8 fa[4], fb[4];
#pragma unroll
    for (int ks = 0; ks < 4; ++ks) {
      fa[ks] = *(const bf16x8*)(&As[ti * 16 + fr][ks * 32 + fk]);
      fb[ks] = *(const bf16x8*)(&As[tj * 16 + fr][ks * 32 + fk]);
    }
    f32x4 g = {0.f, 0.f, 0.f, 0.f};
#pragma unroll
    for (int ks = 0; ks < 4; ++ks)
      g = __builtin_amdgcn_mfma_f32_16x16x32_bf16(fa[ks], fb[ks], g, 0, 0, 0);
    if (ti == tj) {
      if ((c >> 2) == q) rednorm[ti * 16 + c] = g[c & 3];
    } else {
      if (c == ti * 4 + q) {
#pragma unroll
        for (int r = 0; r < 4; ++r) reddot[ti * 16 + q * 4 + r] = g[r];
      }
    }
    if (wave == 0) {
      bf16x8 fc[4];
#pragma unroll
      for (int ks = 0; ks < 4; ++ks)
        fc[ks] = *(const bf16x8*)(&As[32 + fr][ks * 32 + fk]);
      f32x4 g2 = {0.f, 0.f, 0.f, 0.f};
#pragma unroll
      for (int ks = 0; ks < 4; ++ks)
        g2 = __builtin_amdgcn_mfma_f32_16x16x32_bf16(fc[ks], fc[ks], g2, 0, 0, 0);
      if ((c >> 2) == q && c < 8) rednorm[32 + c] = g2[c & 3];
    }
  }
  __syncthreads();

  const int h   = tid >> 3;
  const int sub = tid & 7;
  const int kr  = 32 + (h >> 2);
  float s = 0.f;
#pragma unroll
  for (int j = 0; j < 16; ++j) {
    const int c = sub + 8 * j;
    s += fabsf(code[h][c] - code[kr][c]);
  }
  s += __shfl_down(s, 4, 8);
  s += __shfl_down(s, 2, 8);
  s += __shfl_down(s, 1, 8);
  if (sub == 0) {
    const float invsq = 0.08838834764831843f;  // 1/sqrt(128)
    out[(size_t)b * NH + h] = reddot[h] * invsq;
    const float hamw = (1.0f - s * (1.0f / 64.0f)) *
                       sqrtf(rednorm[h]) * sqrtf(rednorm[kr]) * invsq;
    out[(size_t)(B_TOK * NH) + (size_t)b * NH + h] = hamw;
  }
}

// ---------------- launch ----------------

extern "C" void kernel_launch(void* const* d_in, const int* in_sizes, int n_in,
                              void* d_out, int out_size, void* d_ws, size_t ws_size,
                              hipStream_t stream) {
  const float* hidden = (const float*)d_in[0];   // [8192][4096]
  const float* proj_w = (const float*)d_in[1];   // [4096][6144]
  const float* proj_b = (const float*)d_in[2];   // [6144]
  const float* hash_w = (const float*)d_in[3];   // [128][128]
  float* out = (float*)d_out;                    // [2*262144]

  char* w = (char*)d_ws;
  __bf16* Abf = (__bf16*)(w);                                     // 67,108,864 B
  __bf16* Wt  = (__bf16*)(w + 67108864);                          // 41,943,040 B
  __bf16* QK  = (__bf16*)(w + 67108864 + 41943040);               // 83,886,080 B
  __bf16* hwT = (__bf16*)(w + 67108864 + 41943040 + 83886080);    // 32,768 B

  prep_kernel<<<NB_HID + NB_WT + NB_HASH, 256, 0, stream>>>(hidden, Abf, proj_w, Wt,
                                                            hash_w, hwT);
  gemm_qk<<<1280, 256, 0, stream>>>(Abf, Wt, proj_b, QK);
  phase2_kernel<<<B_TOK, 256, 0, stream>>>(QK, hwT, out);
}